// Round 11
// baseline (43.725 us; speedup 1.0000x reference)
//
#include <hip/hip_runtime.h>

// Resample1d: out[b,c,h,w] = lerp of input1[b,c,h,:] at x = w + disp[b,h,w],
// zeroed where x outside [0, W-1].
// Shapes: input1 (B,C,H,W) f32, input2 (B,1,H,W) f32, out (B,C,H,W) f32.
//
// R11: probe the in-flight-bytes-per-wave axis. CPW=4 with ALL 4 channels'
// loads issued upfront (8 x dwordx4 = 2KB in flight, 2x R10's 1KB), no
// refill ring. R9/R10 showed the tail axis is exhausted at 43.2-43.5us;
// we're still below even a serialized-BW estimate (~33us), so latency is
// exposed somewhere. NT dwordx4 stores (R8), 4*lane+j mapping (R5/R7) kept.
// VGPR ~48-56 (<=64 keeps 8 waves/SIMD — verify in counters).

#define B 4
#define C 64
#define H 256
#define W 512
#define WAVES 4          // waves per block
#define CPW 4            // channels per wave, all prefetched upfront
// grid = (B*H, C/(WAVES*CPW)) = (1024, 4); block = 256

typedef float f32x4 __attribute__((ext_vector_type(4)));

__global__ __launch_bounds__(256) void resample1d_kernel(
    const float* __restrict__ in1,   // (B,C,H,W)
    const float* __restrict__ in2,   // (B,1,H,W)
    float* __restrict__ out)         // (B,C,H,W)
{
    __shared__ float rowbuf[WAVES][W];   // 4 x 2KB, wave-private chunks

    const int tid  = threadIdx.x;
    const int wid  = tid >> 6;
    const int lane = tid & 63;

    const int bh = blockIdx.x;          // 0..B*H-1
    const int b  = bh >> 8;             // / H  (H=256)
    const int cbase = blockIdx.y * (WAVES * CPW) + wid * CPW;

    const size_t chan_stride = (size_t)H * W;
    const float* src = in1 + ((size_t)b * C + cbase) * chan_stride + (size_t)(bh & (H - 1)) * W;
    float*       dst = out + ((size_t)b * C + cbase) * chan_stride + (size_t)(bh & (H - 1)) * W;
    const float* disp_row = in2 + (size_t)bh * W;

    // ---- issue ALL 4 channels' loads + disp loads up front (2KB in flight) ----
    f32x4 pre0[4], pre1[4];
    #pragma unroll
    for (int cc = 0; cc < CPW; ++cc) {
        pre0[cc] = *(const f32x4*)(src + (size_t)cc * chan_stride + 4 * lane);
        pre1[cc] = *(const f32x4*)(src + (size_t)cc * chan_stride + 256 + 4 * lane);
    }
    f32x4 d4[2];
    d4[0] = *(const f32x4*)(disp_row + 4 * lane);
    d4[1] = *(const f32x4*)(disp_row + 256 + 4 * lane);

    // ---- per-lane pixel params: w = 4*lane + 256*g + j (hoisted over c) ----
    int   i0[2][4];
    float w0[2][4], w1[2][4];
    #pragma unroll
    for (int g = 0; g < 2; ++g) {
        #pragma unroll
        for (int j = 0; j < 4; ++j) {
            int w = 4 * lane + 256 * g + j;
            float x = (float)w + d4[g][j];
            bool valid = (x >= 0.0f) && (x <= (float)(W - 1));
            float x0 = floorf(x);
            float frac = x - x0;
            i0[g][j] = (int)fminf(fmaxf(x0, 0.0f), (float)(W - 1));
            w0[g][j] = valid ? (1.0f - frac) : 0.0f;
            w1[g][j] = valid ? frac : 0.0f;
        }
    }

    float* rb = rowbuf[wid];

    #pragma unroll
    for (int cc = 0; cc < CPW; ++cc) {
        // staged regs -> wave-private LDS (ds_write_b128, conflict-free)
        *(f32x4*)(rb + 4 * lane)       = pre0[cc];
        *(f32x4*)(rb + 256 + 4 * lane) = pre1[cc];
        // taps from LDS, lerp, two coalesced dwordx4 NT stores
        float* d = dst + (size_t)cc * chan_stride;
        #pragma unroll
        for (int g = 0; g < 2; ++g) {
            f32x4 r;
            #pragma unroll
            for (int j = 0; j < 4; ++j) {
                int a0 = i0[g][j];
                int a1 = min(a0 + 1, W - 1);
                r[j] = w0[g][j] * rb[a0] + w1[g][j] * rb[a1];
            }
            __builtin_nontemporal_store(r, (f32x4*)(d + 4 * lane + 256 * g));
        }
    }
}

extern "C" void kernel_launch(void* const* d_in, const int* in_sizes, int n_in,
                              void* d_out, int out_size, void* d_ws, size_t ws_size,
                              hipStream_t stream) {
    const float* in1 = (const float*)d_in[0];
    const float* in2 = (const float*)d_in[1];
    float* out = (float*)d_out;

    dim3 grid(B * H, C / (WAVES * CPW)), block(WAVES * 64);
    resample1d_kernel<<<grid, block, 0, stream>>>(in1, in2, out);
}

// Round 12
// 43.274 us; speedup vs baseline: 1.0104x; 1.0104x over previous
//
#include <hip/hip_runtime.h>

// Resample1d: out[b,c,h,w] = lerp of input1[b,c,h,:] at x = w + disp[b,h,w],
// zeroed where x outside [0, W-1].
// Shapes: input1 (B,C,H,W) f32, input2 (B,1,H,W) f32, out (B,C,H,W) f32.
//
// R12: global_load_lds direct staging + counted vmcnt waits. R11 showed the
// compiler sinks plain prefetch loads next to their uses (VGPR_Count stayed
// 32), so HIP-level prefetch depth is illusory. global_load_lds has fixed
// issue order (side-effecting builtin) and writes LDS directly:
//   issue disp(2) -> gl_lds(4) -> vmcnt(4) -> params
//   ch0: vmcnt(2) -> taps -> NT stores; ch1: vmcnt(2) -> taps -> NT stores
// Channel 1's staging stays in flight during channel 0's compute.
// CPW=2 grid (R10 best), NT dwordx4 stores (R8), 4*lane+j mapping (R5/R7).

#define B 4
#define C 64
#define H 256
#define W 512
#define WAVES 4          // waves per block
#define CPW 2            // channels per wave, both staged via gl_lds upfront
// grid = (B*H, C/(WAVES*CPW)) = (1024, 8); block = 256

typedef float f32x4 __attribute__((ext_vector_type(4)));

__device__ __forceinline__ void load_lds16(const float* g, float* l) {
    __builtin_amdgcn_global_load_lds(
        (const __attribute__((address_space(1))) void*)g,
        (__attribute__((address_space(3))) void*)l,
        16, 0, 0);
}

__global__ __launch_bounds__(256) void resample1d_kernel(
    const float* __restrict__ in1,   // (B,C,H,W)
    const float* __restrict__ in2,   // (B,1,H,W)
    float* __restrict__ out)         // (B,C,H,W)
{
    __shared__ float rowbuf[WAVES][CPW][W];   // 4 x 2 x 2KB = 16KB

    const int tid  = threadIdx.x;
    const int wid  = tid >> 6;
    const int lane = tid & 63;

    const int bh = blockIdx.x;          // 0..B*H-1
    const int b  = bh >> 8;             // / H  (H=256)
    const int cbase = blockIdx.y * (WAVES * CPW) + wid * CPW;

    const size_t chan_stride = (size_t)H * W;
    const float* src = in1 + ((size_t)b * C + cbase) * chan_stride + (size_t)(bh & (H - 1)) * W;
    float*       dst = out + ((size_t)b * C + cbase) * chan_stride + (size_t)(bh & (H - 1)) * W;
    const float* disp_row = in2 + (size_t)bh * W;

    // ---- 1) disp loads first (oldest in vmcnt queue) ----
    f32x4 d4[2];
    d4[0] = *(const f32x4*)(disp_row + 4 * lane);
    d4[1] = *(const f32x4*)(disp_row + 256 + 4 * lane);

    // ---- 2) stage both channel rows via direct-to-LDS DMA (4 x 1KB) ----
    // dest is wave-uniform base + lane*16 -> linear row layout, matches reads
    #pragma unroll
    for (int cc = 0; cc < CPW; ++cc) {
        load_lds16(src + (size_t)cc * chan_stride + 4 * lane,        &rowbuf[wid][cc][0]);
        load_lds16(src + (size_t)cc * chan_stride + 256 + 4 * lane,  &rowbuf[wid][cc][256]);
    }

    // ---- 3) wait for disp only (staging stays in flight), compute params ----
    asm volatile("s_waitcnt vmcnt(4)" ::: "memory");
    int   i0[2][4];
    float w0[2][4], w1[2][4];
    #pragma unroll
    for (int g = 0; g < 2; ++g) {
        #pragma unroll
        for (int j = 0; j < 4; ++j) {
            int w = 4 * lane + 256 * g + j;
            float x = (float)w + d4[g][j];
            bool valid = (x >= 0.0f) && (x <= (float)(W - 1));
            float x0 = floorf(x);
            float frac = x - x0;
            i0[g][j] = (int)fminf(fmaxf(x0, 0.0f), (float)(W - 1));
            w0[g][j] = valid ? (1.0f - frac) : 0.0f;
            w1[g][j] = valid ? frac : 0.0f;
        }
    }

    // ---- 4) per channel: counted wait, LDS taps, lerp, NT dwordx4 stores ----
    #pragma unroll
    for (int cc = 0; cc < CPW; ++cc) {
        // wait for this channel's 2 gl_lds (oldest outstanding); ch1's stay in
        // flight during ch0 compute. After ch0's 2 NT stores the queue is
        // {gl3, gl4, st1, st2} -> vmcnt(2) again waits exactly gl3, gl4.
        asm volatile("s_waitcnt vmcnt(2)" ::: "memory");
        const float* rb = rowbuf[wid][cc];
        float* d = dst + (size_t)cc * chan_stride;
        #pragma unroll
        for (int g = 0; g < 2; ++g) {
            f32x4 r;
            #pragma unroll
            for (int j = 0; j < 4; ++j) {
                int a0 = i0[g][j];
                int a1 = min(a0 + 1, W - 1);
                r[j] = w0[g][j] * rb[a0] + w1[g][j] * rb[a1];
            }
            __builtin_nontemporal_store(r, (f32x4*)(d + 4 * lane + 256 * g));
        }
    }
}

extern "C" void kernel_launch(void* const* d_in, const int* in_sizes, int n_in,
                              void* d_out, int out_size, void* d_ws, size_t ws_size,
                              hipStream_t stream) {
    const float* in1 = (const float*)d_in[0];
    const float* in2 = (const float*)d_in[1];
    float* out = (float*)d_out;

    dim3 grid(B * H, C / (WAVES * CPW)), block(WAVES * 64);
    resample1d_kernel<<<grid, block, 0, stream>>>(in1, in2, out);
}